// Round 5
// baseline (677.990 us; speedup 1.0000x reference)
//
#include <hip/hip_runtime.h>
#include <math.h>

// FractalOpponent on MI355X, round 5 (= round 4 with bf16-mirror layout fixed).
// - bf16 mirror of Wv,Wo,Whh,expert (40M elems, ~80MB) built per call in ws.
//   CORRECTED offsets: Whh is HxH*4 = 16M elements (was sized 8M in R4 -> overlap bug).
// - ram_w/ag_w stay fp32 (conversion is traffic-neutral for 3 uses).
// - Last-block (fence+counter) fusion: combine in expert GEMV; fsel/tail1/tail2 in
//   ag GEMVs. 28 kernels total.

#define H 2048
typedef unsigned short u16;

// ---- ws float offsets ----
constexpr int DL_OFF   = 16;                    // dl0@16, dl1@20, dl3@24 (ints 0..15 = counters)
constexpr int GT_OFF   = 32;                    // gates template [8192]
constexpr int NODE_OFF = 8224;                  // 5 x NODESZ
constexpr int NODESZ   = 26624;
constexpr int THVo = 0, ATTNo = 2048, GATESo = 4096, EOo = 12288, SOo = 20480, CSo = 22528, HPo = 24576;
constexpr int FIN_OFF  = NODE_OFF + 5 * NODESZ; // 3 x FINSZ
constexpr int FINSZ    = 8192;
constexpr int HNo = 0, AGGo = 2048, ANCo = 4096, GACCo = 6144;
constexpr int RH1_OFF  = FIN_OFF + 3 * FINSZ;
constexpr int RF1_OFF  = RH1_OFF + 2048;
constexpr int RC1_OFF  = RH1_OFF + 4096;
constexpr size_t BF_BYTE_OFF = 688384;          // aligned start of bf16 mirror
// bf16 element offsets (sizes: Wv 4M | Wo 4M | Whh 16M | expert 16M)
constexpr size_t oWv = 0;
constexpr size_t oWo = 4194304;
constexpr size_t oWhh = 8388608;
constexpr size_t oEx = 25165824;
constexpr size_t BF_CONV_ELEMS = 41943040;      // 40M

__device__ __forceinline__ float sigm(float v) { return 1.f / (1.f + expf(-v)); }

__device__ __forceinline__ int dsteps(const float* dl, int mx) {
  float l0 = dl[0], l1 = dl[1], l2 = dl[2];
  int ch = 0; float bv = l0;
  if (l1 > bv) { bv = l1; ch = 1; }
  if (l2 > bv) { bv = l2; ch = 2; }
  return ch < mx ? ch : mx;
}

// pred codes: 0 always | 1 s0>=1 | 2 s0>=1&&s1>=1 | 3 s0>=2 | 4 s0>=2&&s3>=1
__device__ __forceinline__ bool pred(const float* ws, int code) {
  if (code == 0) return true;
  const int s0 = dsteps(ws + DL_OFF, 2);
  switch (code) {
    case 1: return s0 >= 1;
    case 2: return s0 >= 1 && dsteps(ws + DL_OFF + 4, 1) >= 1;
    case 3: return s0 >= 2;
    case 4: return s0 >= 2 && dsteps(ws + DL_OFF + 8, 1) >= 1;
  }
  return true;
}

__device__ __forceinline__ float bfl(unsigned u) { union { unsigned x; float f; } c; c.x = u << 16; return c.f; }
__device__ __forceinline__ float bfh(unsigned u) { union { unsigned x; float f; } c; c.x = u & 0xFFFF0000u; return c.f; }
__device__ __forceinline__ u16 f2bf(float f) {
  unsigned u = __float_as_uint(f);
  u += 0x7FFFu + ((u >> 16) & 1u);
  return (u16)(u >> 16);
}

template <typename WT> struct W8;
template <> struct W8<u16> {
  static __device__ __forceinline__ void load(const u16* p, float* w) {
    uint4 u = *reinterpret_cast<const uint4*>(p);
    w[0] = bfl(u.x); w[1] = bfh(u.x); w[2] = bfl(u.y); w[3] = bfh(u.y);
    w[4] = bfl(u.z); w[5] = bfh(u.z); w[6] = bfl(u.w); w[7] = bfh(u.w);
  }
};
template <> struct W8<float> {
  static __device__ __forceinline__ void load(const float* p, float* w) {
    float4 a = *reinterpret_cast<const float4*>(p);
    float4 b = *reinterpret_cast<const float4*>(p + 4);
    w[0] = a.x; w[1] = a.y; w[2] = a.z; w[3] = a.w;
    w[4] = b.x; w[5] = b.y; w[6] = b.z; w[7] = b.w;
  }
};

// ---------- tail duties (run by last block of the hosting kernel) ----------
__device__ void tail_fsel(float* ws) {
  if (dsteps(ws + DL_OFF, 2) < 1) return;
  const bool deep = dsteps(ws + DL_OFF + 4, 1) >= 1;
  float* rh1 = ws + RH1_OFF; float* rf1 = ws + RF1_OFF; float* rc1 = ws + RC1_OFF;
  const float* fin = ws + FIN_OFF;
  const float* n1 = ws + NODE_OFF + 1 * NODESZ;
  const float* n2 = ws + NODE_OFF + 2 * NODESZ;
  for (int jj = threadIdx.x; jj < H; jj += 256) {
    if (deep) {
      const float gv = sigm(fin[GACCo + jj]);
      rh1[jj] = gv * fin[ANCo + jj] + (1.f - gv) * fin[HNo + jj];
      rf1[jj] = n2[SOo + jj]; rc1[jj] = n2[CSo + jj];
    } else {
      rh1[jj] = n1[HPo + jj]; rf1[jj] = n1[SOo + jj]; rc1[jj] = n1[CSo + jj];
    }
  }
}

__device__ void tail1(float* ws, float* out) {
  const int s0 = dsteps(ws + DL_OFF, 2);
  if (s0 < 1) return;
  const bool deep3 = dsteps(ws + DL_OFF + 8, 1) >= 1;
  const float* rh1 = ws + RH1_OFF; const float* rf1 = ws + RF1_OFF; const float* rc1 = ws + RC1_OFF;
  const float* fin3 = ws + FIN_OFF + FINSZ;
  float* fin0 = ws + FIN_OFF + 2 * FINSZ;
  const float* n3 = ws + NODE_OFF + 3 * NODESZ;
  const float* n4 = ws + NODE_OFF + 4 * NODESZ;
  const float* n0 = ws + NODE_OFF;
  for (int jj = threadIdx.x; jj < H; jj += 256) {
    float rh3 = 0.f, rf3v = 0.f, rc3v = 0.f;
    if (s0 >= 2) {
      if (deep3) {
        const float gv = sigm(fin3[GACCo + jj]);
        rh3 = gv * fin3[ANCo + jj] + (1.f - gv) * fin3[HNo + jj];
        rf3v = n4[SOo + jj]; rc3v = n4[CSo + jj];
      } else { rh3 = n3[HPo + jj]; rf3v = n3[SOo + jj]; rc3v = n3[CSo + jj]; }
    }
    const float r1 = rh1[jj];
    float ag = n0[HPo + jj] - 0.5f * r1;
    float hc, oF, oC;
    if (s0 >= 2) { ag += (1.f / 3.f) * rh3; hc = rh3; oF = rf3v; oC = rc3v; }
    else { hc = r1; oF = rf1[jj]; oC = rc1[jj]; }
    fin0[AGGo + jj] = ag; fin0[HNo + jj] = hc;
    out[jj] = oF; out[2 * H + jj] = oC;
  }
}

__device__ void tail2(float* ws, float* out) {
  const int s0 = dsteps(ws + DL_OFF, 2);
  const float* n0 = ws + NODE_OFF;
  const float* fin0 = ws + FIN_OFF + 2 * FINSZ;
  for (int jj = threadIdx.x; jj < H; jj += 256) {
    if (s0 == 0) {
      out[jj] = n0[SOo + jj]; out[H + jj] = n0[HPo + jj]; out[2 * H + jj] = n0[CSo + jj];
    } else {
      const float gv = sigm(fin0[GACCo + jj]);
      out[H + jj] = gv * fin0[ANCo + jj] + (1.f - gv) * fin0[HNo + jj];
    }
  }
}

// ---------- conversion + init ----------
__global__ void __launch_bounds__(256) k_convinit(
    const float* Wv, const float* Wo, const float* Whh, const float* Wex,
    const float* b_lstm, const float* expert_b, const float* ram_b, const float* ag_b,
    float* ws, u16* bf, int doConv)
{
  const int ib = (int)blockIdx.x - ((int)gridDim.x - 8);
  if (ib >= 0) {
    const int t = ib * 256 + threadIdx.x;  // 0..2047
    if (t < 16) ((unsigned*)ws)[t] = 0u;
    for (int i = t; i < 8192; i += 2048) ws[GT_OFF + i] = b_lstm[i];
    for (int n = 0; n < 5; ++n) {
      float* nb = ws + NODE_OFF + n * NODESZ;
      for (int i = t; i < 4096; i += 2048) nb[i] = 0.f;                 // t_hv + attn
      for (int i = t; i < 8192; i += 2048) nb[EOo + i] = expert_b[i];
    }
    for (int f = 0; f < 3; ++f) {
      float* fb = ws + FIN_OFF + f * FINSZ;
      fb[ANCo + t] = ram_b[t];
      fb[GACCo + t] = ag_b[t];
    }
    return;
  }
  if (!doConv) return;
  const size_t nthr = (size_t)(gridDim.x - 8) * 256;
  const size_t c0 = (size_t)blockIdx.x * 256 + threadIdx.x;
  for (size_t c = c0; c < BF_CONV_ELEMS / 4; c += nthr) {
    const size_t e = c * 4;
    const float* src; size_t off;
    if (e < oWo) { src = Wv; off = e; }
    else if (e < oWhh) { src = Wo; off = e - oWo; }
    else if (e < oEx) { src = Whh; off = e - oWhh; }
    else { src = Wex; off = e - oEx; }
    const float4 v = *reinterpret_cast<const float4*>(src + off);
    ushort4 o;
    o.x = f2bf(v.x); o.y = f2bf(v.y); o.z = f2bf(v.z); o.w = f2bf(v.w);
    *reinterpret_cast<ushort4*>(bf + e) = o;
  }
}

// ---------- GEMV: y[j] += sum_i x[i]*W[i,j], grid 256, 512 cols/group ----------
// TAIL: 0 none | 1 fsel | 2 tail1 | 3 tail2 (tail runs regardless of pred)
template <typename WT, int TAIL>
__global__ void __launch_bounds__(256) k_gemv(
    const float* __restrict__ xA, const float* __restrict__ xB, int splitPt,
    const WT* __restrict__ W, float* __restrict__ y, int K, int N,
    float* ws, float* out, int predCode,
    const float* copySrc, float* copyDst, int copyN, int ctrIdx)
{
  const bool ok = pred(ws, predCode);
  if (TAIL == 0 && !ok) return;
  const int tid = threadIdx.x, lane = tid & 63, tsub = tid >> 6;
  __shared__ float red[2048];
  if (ok) {
    if (copySrc) {
      const int gid = blockIdx.x * 256 + tid;
      if (gid < copyN) copyDst[gid] = copySrc[gid];
    }
    const int G = N >> 9;
    const int KS = gridDim.x / G;
    const int g = blockIdx.x % G;
    const int s = blockIdx.x / G;
    const int chunk = K / KS, rpt = chunk >> 2;
    const int i0 = s * chunk + tsub * rpt;
    const int j = (g << 9) + (lane << 3);
    const WT* Wp = W + (size_t)i0 * N + j;
    float acc[8] = {0.f, 0.f, 0.f, 0.f, 0.f, 0.f, 0.f, 0.f};
    for (int t = 0; t < rpt; ++t) {
      const int i = i0 + t;
      const float xi = (i < splitPt) ? xA[i] : xB[i - splitPt];
      float w[8];
      W8<WT>::load(Wp, w);
#pragma unroll
      for (int q = 0; q < 8; ++q) acc[q] = fmaf(xi, w[q], acc[q]);
      Wp += N;
    }
#pragma unroll
    for (int q = 0; q < 8; ++q) red[tid * 8 + q] = acc[q];
    __syncthreads();
    if (tsub == 0) {
#pragma unroll
      for (int q = 0; q < 8; ++q) {
        const float s4 = red[tid * 8 + q] + red[(tid + 64) * 8 + q] +
                         red[(tid + 128) * 8 + q] + red[(tid + 192) * 8 + q];
        atomicAdd(&y[j + q], s4);
      }
    }
  }
  if (TAIL != 0) {
    __threadfence();
    __syncthreads();
    __shared__ int lastF;
    if (tid == 0) lastF = (atomicAdd((unsigned*)ws + ctrIdx, 1u) == gridDim.x - 1);
    __syncthreads();
    if (lastF) {
      __threadfence();
      if (TAIL == 1) tail_fsel(ws);
      else if (TAIL == 2) tail1(ws, out);
      else tail2(ws, out);
    }
  }
}

// ---------- expert GEMV + fused LSTM + fused combine (last block) ----------
template <typename WT>
__global__ void __launch_bounds__(256) k_expert(
    const float* __restrict__ gates, const float* __restrict__ c_in,
    const WT* __restrict__ Wex, float* ws, int predCode, int nodeIdx, int ctrIdx,
    int dlIdx, int finIdx, float damping, int phpNodeIdx,
    const float* __restrict__ router_w, const float* __restrict__ router_b,
    const float* __restrict__ dr_w, const float* __restrict__ dr_b)
{
  if (!pred(ws, predCode)) return;
  float* nb = ws + NODE_OFF + nodeIdx * NODESZ;
  float* eo = nb + EOo; float* so = nb + SOo; float* cs = nb + CSo; float* hp = nb + HPo;
  const int tid = threadIdx.x, lane = tid & 63, w = tid >> 6;
  const int g = blockIdx.x & 15, s = blockIdx.x >> 4;   // G=16, KS=16
  const int i0 = s * 128;
  __shared__ float h2s[128];
  __shared__ float red[2048];
  if (tid < 128) {
    const int i = i0 + tid;
    const float gi = gates[i], gf = gates[H + i], gg = gates[2 * H + i], go = gates[3 * H + i];
    const float c2 = sigm(gf) * c_in[i] + sigm(gi) * tanhf(gg);
    const float h2 = sigm(go) * tanhf(c2);
    h2s[tid] = h2;
    if (g == 0) { so[i] = h2; cs[i] = c2; }
  }
  __syncthreads();
  const int j = (g << 9) + (lane << 3);
  const int e = j >> 11, k = j & (H - 1);
  const WT* Wp = Wex + ((size_t)e << 22) + (size_t)(i0 + w * 32) * H + k;
  float acc[8] = {0.f, 0.f, 0.f, 0.f, 0.f, 0.f, 0.f, 0.f};
  for (int t = 0; t < 32; ++t) {
    const float xi = h2s[w * 32 + t];
    float wv[8];
    W8<WT>::load(Wp, wv);
#pragma unroll
    for (int q = 0; q < 8; ++q) acc[q] = fmaf(xi, wv[q], acc[q]);
    Wp += H;
  }
#pragma unroll
  for (int q = 0; q < 8; ++q) red[tid * 8 + q] = acc[q];
  __syncthreads();
  if (w == 0) {
#pragma unroll
    for (int q = 0; q < 8; ++q) {
      const float s4 = red[tid * 8 + q] + red[(tid + 64) * 8 + q] +
                       red[(tid + 128) * 8 + q] + red[(tid + 192) * 8 + q];
      atomicAdd(&eo[j + q], s4);
    }
  }
  // last-block combine
  __threadfence();
  __syncthreads();
  __shared__ int lastF;
  if (tid == 0) lastF = (atomicAdd((unsigned*)ws + ctrIdx, 1u) == gridDim.x - 1);
  __syncthreads();
  if (!lastF) return;
  __threadfence();
  // router logits
  float r0 = 0.f, r1 = 0.f, r2 = 0.f, r3 = 0.f;
  for (int i = tid; i < H; i += 256) {
    const float hh = so[i];
    const float4 rw = *reinterpret_cast<const float4*>(router_w + i * 4);
    r0 = fmaf(hh, rw.x, r0); r1 = fmaf(hh, rw.y, r1);
    r2 = fmaf(hh, rw.z, r2); r3 = fmaf(hh, rw.w, r3);
  }
  float4* red4 = reinterpret_cast<float4*>(red);
  red4[tid] = make_float4(r0, r1, r2, r3);
  __syncthreads();
  for (int off = 128; off > 0; off >>= 1) {
    if (tid < off) {
      const float4 b = red4[tid + off];
      red4[tid].x += b.x; red4[tid].y += b.y; red4[tid].z += b.z; red4[tid].w += b.w;
    }
    __syncthreads();
  }
  const float4 L = red4[0];
  __syncthreads();
  const float l0 = L.x + router_b[0], l1 = L.y + router_b[1];
  const float l2 = L.z + router_b[2], l3 = L.w + router_b[3];
  const float m = fmaxf(fmaxf(l0, l1), fmaxf(l2, l3));
  const float e0 = expf(l0 - m), e1 = expf(l1 - m), e2 = expf(l2 - m), e3 = expf(l3 - m);
  const float inv = 1.f / (e0 + e1 + e2 + e3);
  const float p0 = e0 * inv, p1 = e1 * inv, p2 = e2 * inv, p3 = e3 * inv;
  if (finIdx >= 0) {  // leaf: fuse parent's Ramanujan prep
    const float* php = ws + NODE_OFF + phpNodeIdx * NODESZ + HPo;
    float* hn = ws + FIN_OFF + finIdx * FINSZ + HNo;
    float* agg = ws + FIN_OFF + finIdx * FINSZ + AGGo;
    for (int jj = tid; jj < H; jj += 256) {
      const float v = p0 * eo[jj] + p1 * eo[H + jj] + p2 * eo[2 * H + jj] + p3 * eo[3 * H + jj];
      const float h0 = php[jj];
      const float hnv = h0 + damping * (v - h0);
      hn[jj] = hnv;
      agg[jj] = h0 - 0.5f * hnv;
    }
  } else {
    float* dl = ws + DL_OFF + dlIdx * 4;
    float d0 = 0.f, d1 = 0.f, d2 = 0.f;
    for (int jj = tid; jj < H; jj += 256) {
      const float v = p0 * eo[jj] + p1 * eo[H + jj] + p2 * eo[2 * H + jj] + p3 * eo[3 * H + jj];
      hp[jj] = v;
      d0 = fmaf(v, dr_w[jj * 3 + 0], d0);
      d1 = fmaf(v, dr_w[jj * 3 + 1], d1);
      d2 = fmaf(v, dr_w[jj * 3 + 2], d2);
    }
    red4[tid] = make_float4(d0, d1, d2, 0.f);
    __syncthreads();
    for (int off = 128; off > 0; off >>= 1) {
      if (tid < off) {
        const float4 b = red4[tid + off];
        red4[tid].x += b.x; red4[tid].y += b.y; red4[tid].z += b.z;
      }
      __syncthreads();
    }
    if (tid == 0) {
      dl[0] = red4[0].x + dr_b[0];
      dl[1] = red4[0].y + dr_b[1];
      dl[2] = red4[0].z + dr_b[2];
    }
  }
}

extern "C" void kernel_launch(void* const* d_in, const int* in_sizes, int n_in,
                              void* d_out, int out_size, void* d_ws, size_t ws_size,
                              hipStream_t stream) {
  const float* x        = (const float*)d_in[0];
  const float* h0in     = (const float*)d_in[1];
  const float* c0in     = (const float*)d_in[2];
  const float* Wv       = (const float*)d_in[5];
  const float* Wo       = (const float*)d_in[6];
  const float* Wih      = (const float*)d_in[7];
  const float* Whh      = (const float*)d_in[8];
  const float* b_lstm   = (const float*)d_in[9];
  const float* router_w = (const float*)d_in[10];
  const float* router_b = (const float*)d_in[11];
  const float* expert_w = (const float*)d_in[12];
  const float* expert_b = (const float*)d_in[13];
  const float* dr_w     = (const float*)d_in[14];
  const float* dr_b     = (const float*)d_in[15];
  const float* ram_w    = (const float*)d_in[16];
  const float* ram_b    = (const float*)d_in[17];
  const float* ag_w     = (const float*)d_in[18];
  const float* ag_b     = (const float*)d_in[19];
  float* out = (float*)d_out;
  float* ws  = (float*)d_ws;

  const bool useBf = ws_size >= BF_BYTE_OFF + BF_CONV_ELEMS * 2 + 1024;
  u16* bf = (u16*)((char*)d_ws + BF_BYTE_OFF);
  const u16 *bWv = bf + oWv, *bWo = bf + oWo, *bWhh = bf + oWhh, *bEx = bf + oEx;

  auto nbuf = [&](int n) { return ws + NODE_OFF + n * NODESZ; };
  float* fin0 = ws + FIN_OFF;
  float* fin1 = ws + FIN_OFF + FINSZ;
  float* fin2 = ws + FIN_OFF + 2 * FINSZ;

  // bf16-or-fp32 GEMV (for node weights, no tail)
  auto gemvB = [&](const float* xA, const float* xB, int splitPt, const u16* Wb, const float* Wf,
                   float* y, int K, int N, int predCode,
                   const float* cpS, float* cpD, int cpN) {
    if (useBf)
      k_gemv<u16, 0><<<256, 256, 0, stream>>>(xA, xB, splitPt, Wb, y, K, N, ws, out, predCode, cpS, cpD, cpN, 0);
    else
      k_gemv<float, 0><<<256, 256, 0, stream>>>(xA, xB, splitPt, Wf, y, K, N, ws, out, predCode, cpS, cpD, cpN, 0);
  };
  // fp32-only GEMV with tail option (ram/ag/Wih)
  auto gemvF = [&](const float* xA, const float* xB, int splitPt, const float* Wf,
                   float* y, int K, int N, int predCode, int tail, int ctrIdx) {
    switch (tail) {
      case 0: k_gemv<float, 0><<<256, 256, 0, stream>>>(xA, xB, splitPt, Wf, y, K, N, ws, out, predCode, nullptr, nullptr, 0, ctrIdx); break;
      case 1: k_gemv<float, 1><<<256, 256, 0, stream>>>(xA, xB, splitPt, Wf, y, K, N, ws, out, predCode, nullptr, nullptr, 0, ctrIdx); break;
      case 2: k_gemv<float, 2><<<256, 256, 0, stream>>>(xA, xB, splitPt, Wf, y, K, N, ws, out, predCode, nullptr, nullptr, 0, ctrIdx); break;
      default: k_gemv<float, 3><<<256, 256, 0, stream>>>(xA, xB, splitPt, Wf, y, K, N, ws, out, predCode, nullptr, nullptr, 0, ctrIdx); break;
    }
  };

  // 1. conversion + init
  k_convinit<<<useBf ? 2056 : 8, 256, 0, stream>>>(Wv, Wo, Whh, expert_w,
                                                   b_lstm, expert_b, ram_b, ag_b,
                                                   ws, bf, useBf ? 1 : 0);
  // 2. gates template += x @ Wih (fp32, used once)
  gemvF(x, x, H, Wih, ws + GT_OFF, H, 4 * H, 0, 0, 0);

  // node: Wv(+gates copy) -> Wo -> Whh -> expert(+LSTM+combine)
  auto node = [&](int n, const float* hv, const float* cv, int predCode, int ctrIdx,
                  int dlIdx, int finIdx, float damping, int phpNodeIdx) {
    float* nb = nbuf(n);
    gemvB(hv, hv, H, bWv, Wv, nb + THVo, H, H, predCode, ws + GT_OFF, nb + GATESo, 8192);
    gemvB(nb + THVo, nb + THVo, H, bWo, Wo, nb + ATTNo, H, H, predCode, nullptr, nullptr, 0);
    gemvB(nb + ATTNo, nb + ATTNo, H, bWhh, Whh, nb + GATESo, H, 4 * H, predCode, nullptr, nullptr, 0);
    if (useBf)
      k_expert<u16><<<256, 256, 0, stream>>>(nb + GATESo, cv, bEx, ws, predCode, n, ctrIdx,
                                             dlIdx, finIdx, damping, phpNodeIdx,
                                             router_w, router_b, dr_w, dr_b);
    else
      k_expert<float><<<256, 256, 0, stream>>>(nb + GATESo, cv, expert_w, ws, predCode, n, ctrIdx,
                                               dlIdx, finIdx, damping, phpNodeIdx,
                                               router_w, router_b, dr_w, dr_b);
  };

  // N0
  node(0, h0in, c0in, 0, 0, 0, -1, 0.f, 0);
  // N1 (s0>=1)
  node(1, nbuf(0) + HPo, nbuf(0) + CSo, 1, 1, 1, -1, 0.f, 0);
  // N2 leaf (s0>=1 && s1>=1); combine writes fin0.hn/agg from php=hp1
  node(2, nbuf(1) + HPo, nbuf(1) + CSo, 2, 2, -1, 0, 0.25f, 1);
  // N1 finalize: ram -> ag(+fsel)
  gemvF(fin0 + AGGo, nbuf(1) + HPo, H, ram_w, fin0 + ANCo, 2 * H, H, 2, 0, 0);
  gemvF(fin0 + HNo, fin0 + ANCo, H, ag_w, fin0 + GACCo, 2 * H, H, 2, 1, 5);
  // N3 (s0>=2), inputs rh1/rc1
  node(3, ws + RH1_OFF, ws + RC1_OFF, 3, 3, 2, -1, 0.f, 0);
  // N4 leaf (s0>=2 && s3>=1)
  node(4, nbuf(3) + HPo, nbuf(3) + CSo, 4, 4, -1, 1, 0.25f, 3);
  // N3 finalize: ram -> ag(+tail1)
  gemvF(fin1 + AGGo, nbuf(3) + HPo, H, ram_w, fin1 + ANCo, 2 * H, H, 4, 0, 0);
  gemvF(fin1 + HNo, fin1 + ANCo, H, ag_w, fin1 + GACCo, 2 * H, H, 4, 2, 6);
  // N0 finalize: ram -> ag(+tail2)
  gemvF(fin2 + AGGo, nbuf(0) + HPo, H, ram_w, fin2 + ANCo, 2 * H, H, 1, 0, 0);
  gemvF(fin2 + HNo, fin2 + ANCo, H, ag_w, fin2 + GACCo, 2 * H, H, 1, 3, 7);
}